// Round 6
// baseline (53.357 us; speedup 1.0000x reference)
//
#include <hip/hip_runtime.h>
#include <hip/hip_bf16.h>
#include <stdint.h>

#define B_ 2
#define N_ 3000
#define F_ 64
#define H_ 4
#define D_ 32
#define K_ 128          // H_*D_ output feature cols
#define KT_ 9           // 9 k-tiles of 16 -> 144 cols (128 feat + 4 denom + 12 pad)
#define NCH_ 94         // ceil(3000/32) m-chunks (3008 padded)
#define NROWT_ 188      // ceil(3000/16) row tiles per batch
#define S_ 8            // split-K factor (blocks per row-tile)
#define PT_ 2304        // partial tile floats: 36 x 64

typedef short bf16x8 __attribute__((ext_vector_type(8)));
typedef float f32x4  __attribute__((ext_vector_type(4)));

__device__ __forceinline__ unsigned short f2bf(float f) {
    uint32_t x = __float_as_uint(f);
    return (unsigned short)((x + 0x7FFFu + ((x >> 16) & 1u)) >> 16);  // RNE
}

// ---- Pass 1: feat[b][h][n][d] = h . kernel ; e2[b][h][n] = feat . att_k2 ; node_mask
__global__ void k_feat(const float* __restrict__ hin, const float* __restrict__ kern,
                       const float* __restrict__ ak2,
                       float* __restrict__ feat, float* __restrict__ e2,
                       float* __restrict__ nmask) {
    int b = blockIdx.x / N_;
    int n = blockIdx.x % N_;
    __shared__ float hrow[F_];
    int tid = threadIdx.x;                       // 128 threads: (h = tid>>5, d = tid&31)
    if (tid < F_) hrow[tid] = hin[(size_t)(b * N_ + n) * F_ + tid];
    __syncthreads();
    int hh = tid >> 5, d = tid & 31;
    float acc = 0.f;
    #pragma unroll
    for (int f = 0; f < F_; ++f)
        acc = fmaf(hrow[f], kern[(hh * F_ + f) * D_ + d], acc);
    feat[((size_t)(b * H_ + hh) * N_ + n) * D_ + d] = acc;
    float v = acc * ak2[hh * D_ + d];
    #pragma unroll
    for (int o = 16; o >= 1; o >>= 1) v += __shfl_xor(v, o, 32);
    if (d == 0) e2[(size_t)(b * H_ + hh) * N_ + n] = v;
    unsigned long long bal = __ballot(tid < F_ && hrow[tid & (F_ - 1)] != 0.0f);
    if (tid == 0) nmask[b * N_ + n] = (bal != 0ull) ? 1.0f : 0.0f;
}

// ---- Pass 2: G in MFMA-B-fragment order: G[((b*94+ch)*9+t)*64 + lane] = ushort8
//      lane: rg=lane>>4, col=lane&15 ; element j -> Gmat[m = ch*32+rg*8+j][k = t*16+col]
//      Gmat[m][k<128] = w[h][m]*feat[h][m][d] (h=k>>5,d=k&31); k in 128..131 -> w[k-128][m]; else 0
//      w[h][m] = exp(e2[h][m])  (max-subtraction cancels in the ratio; |e2|~O(1) so no overflow)
__global__ void k_G(const float* __restrict__ feat, const float* __restrict__ e2,
                    bf16x8* __restrict__ G) {
    int idx = blockIdx.x * blockDim.x + threadIdx.x;
    const int total = B_ * NCH_ * KT_ * 64;
    if (idx >= total) return;
    int lane = idx & 63;
    int t  = (idx >> 6) % KT_;
    int ch = ((idx >> 6) / KT_) % NCH_;
    int b  = idx / (64 * KT_ * NCH_);
    int rg = lane >> 4, col = lane & 15;
    int k  = t * 16 + col;
    int m0 = ch * 32 + rg * 8;
    float vals[8];
    if (k < K_ + H_) {
        int hh, d; bool wonly;
        if (k < K_) { hh = k >> 5; d = k & 31; wonly = false; }
        else        { hh = k - K_; d = 0;      wonly = true;  }
        const float* e2p = e2 + (size_t)(b * H_ + hh) * N_;
        const float* fp  = feat + (size_t)(b * H_ + hh) * N_ * D_ + d;
        #pragma unroll
        for (int j = 0; j < 8; ++j) {
            int m = m0 + j;
            float v = 0.f;
            if (m < N_) {
                float w = __expf(e2p[m]);
                v = wonly ? w : w * fp[(size_t)m * D_];
            }
            vals[j] = v;
        }
    } else {
        #pragma unroll
        for (int j = 0; j < 8; ++j) vals[j] = 0.f;
    }
    union { bf16x8 v; unsigned short u[8]; } o;
    #pragma unroll
    for (int j = 0; j < 8; ++j) o.u[j] = f2bf(vals[j]);
    G[idx] = o.v;
}

// ---- Pass 3 helpers: register double-buffered load set + MFMA compute.
__device__ __forceinline__ void loadsetA(const float* __restrict__ arow, int ch, int rg,
                                         f32x4& f0, f32x4& f1) {
    if (ch == NCH_ - 1 && rg == 3) {              // m=3000..3007: out of range
        f0 = (f32x4){0.f, 0.f, 0.f, 0.f};
        f1 = (f32x4){0.f, 0.f, 0.f, 0.f};
    } else {
        const f32x4* p = (const f32x4*)(arow + ch * 32 + rg * 8);
        f0 = p[0]; f1 = p[1];
    }
}

__device__ __forceinline__ void loadsetG(const bf16x8* __restrict__ Gb, int ch,
                                         bf16x8 (&g)[KT_]) {
    const bf16x8* p = Gb + (size_t)ch * KT_ * 64;
    #pragma unroll
    for (int t = 0; t < KT_; ++t) g[t] = p[t * 64];
}

__device__ __forceinline__ void computeset(const f32x4& f0, const f32x4& f1,
                                           const bf16x8 (&g)[KT_], f32x4 (&acc)[KT_]) {
    union { uint32_t u[4]; bf16x8 v; } af;        // bf16 1.0 = 0x3F80, exact 0/1
    af.u[0] = ((f0.x != 0.f) ? 0x3F80u : 0u) | ((f0.y != 0.f) ? 0x3F800000u : 0u);
    af.u[1] = ((f0.z != 0.f) ? 0x3F80u : 0u) | ((f0.w != 0.f) ? 0x3F800000u : 0u);
    af.u[2] = ((f1.x != 0.f) ? 0x3F80u : 0u) | ((f1.y != 0.f) ? 0x3F800000u : 0u);
    af.u[3] = ((f1.z != 0.f) ? 0x3F80u : 0u) | ((f1.w != 0.f) ? 0x3F800000u : 0u);
    #pragma unroll
    for (int t = 0; t < KT_; ++t)
        acc[t] = __builtin_amdgcn_mfma_f32_16x16x32_bf16(af.v, g[t], acc[t], 0, 0, 0);
}

// ---- Pass 3: split-K GEMM. Grid = B x NROWT x S_. Block (b, rt, s) reduces chunk
//      range [s*94/8, (s+1)*94/8) for 16 rows x 144 cols, 4 waves sub-split it,
//      LDS cross-wave reduction, write 36x64 f32 partial to ws.
__global__ void __launch_bounds__(256, 2) k_main(
        const float* __restrict__ a, const bf16x8* __restrict__ G,
        float* __restrict__ partial) {
    int bid = blockIdx.x;
    int s  = bid % S_;
    int rt = (bid / S_) % NROWT_;
    int b  = bid / (S_ * NROWT_);
    int nbase = rt * 16;
    int w = threadIdx.x >> 6;                     // wave 0..3
    int l = threadIdx.x & 63;
    int rg = l >> 4, col = l & 15;
    int arow_i = nbase + col;                     // A-frag row = lane&15
    int aclamp = min(arow_i, N_ - 1);
    const float* arow = a + (size_t)(b * N_ + aclamp) * N_;
    const bf16x8* Gb = G + (size_t)b * NCH_ * KT_ * 64 + l;

    // split s covers [g0, g1); wave w covers [c0, c1) within it
    int g0 = (s * NCH_) / S_, g1 = ((s + 1) * NCH_) / S_;
    int len = g1 - g0;
    int c0 = g0 + (w * len) / 4;
    int c1 = g0 + ((w + 1) * len) / 4;

    f32x4 acc[KT_];
    #pragma unroll
    for (int t = 0; t < KT_; ++t) acc[t] = (f32x4){0.f, 0.f, 0.f, 0.f};

    // software pipeline: prefetch set B while computing set A
    f32x4 aA0, aA1, aB0, aB1;
    bf16x8 gA[KT_], gB[KT_];
    loadsetA(arow, c0, rg, aA0, aA1);
    loadsetG(Gb, c0, gA);
    int ch = c0;
    for (;;) {
        if (ch + 1 < c1) { loadsetA(arow, ch + 1, rg, aB0, aB1); loadsetG(Gb, ch + 1, gB); }
        computeset(aA0, aA1, gA, acc);
        if (++ch >= c1) break;
        if (ch + 1 < c1) { loadsetA(arow, ch + 1, rg, aA0, aA1); loadsetG(Gb, ch + 1, gA); }
        computeset(aB0, aB1, gB, acc);
        if (++ch >= c1) break;
    }

    // cross-wave reduction in LDS, then coalesced partial write
    __shared__ float red[4][KT_ * 4][64];         // 36,864 B
    #pragma unroll
    for (int t = 0; t < KT_; ++t)
        #pragma unroll
        for (int r = 0; r < 4; ++r)
            red[w][t * 4 + r][l] = acc[t][r];
    __syncthreads();
    float* pout = partial + (size_t)bid * PT_;
    #pragma unroll
    for (int k = 0; k < 9; ++k) {
        int flat = threadIdx.x + k * 256;         // 0..2303
        int x = flat >> 6, y = flat & 63;
        pout[flat] = red[0][x][y] + red[1][x][y] + red[2][x][y] + red[3][x][y];
    }
}

// ---- Pass 4: sum 8 partials per row-tile + fused epilogue (divide/bias/relu/mask)
__global__ void __launch_bounds__(256) k_red(
        const float* __restrict__ partial, const float* __restrict__ bias,
        const float* __restrict__ nmask, float* __restrict__ out) {
    int rt = blockIdx.x % NROWT_;
    int b  = blockIdx.x / NROWT_;
    int nbase = rt * 16;
    int tid = threadIdx.x;
    __shared__ float sm[PT_];
    const float* pbase = partial + (size_t)((b * NROWT_ + rt) * S_) * PT_;
    #pragma unroll
    for (int k = 0; k < 9; ++k) {
        int flat = tid + k * 256;
        float s = 0.f;
        #pragma unroll
        for (int sp = 0; sp < S_; ++sp) s += pbase[(size_t)sp * PT_ + flat];
        sm[flat] = s;
    }
    __syncthreads();
    #pragma unroll
    for (int k = 0; k < 9; ++k) {
        int flat = tid + k * 256;
        if (flat < 2048) {                        // tiles 0..7 are outputs
            int t4r = flat >> 6;                  // t*4+r
            int t = t4r >> 2, r = t4r & 3;
            int lane = flat & 63;
            int rg = lane >> 4, col = lane & 15;
            int rowi = rg * 4 + r;
            int n = nbase + rowi;
            if (n < N_) {
                int hh = t >> 1;
                int r2 = rowi & 3, rg2 = rowi >> 2;
                float den = sm[(32 + r2) * 64 + (rg2 << 4) + hh];
                float v = (den > 0.f) ? sm[flat] / den : 0.f;
                v += bias[t * 16 + col];
                v = fmaxf(v, 0.f);
                v *= nmask[b * N_ + n];
                out[(size_t)(b * N_ + n) * K_ + t * 16 + col] = v;
            }
        }
    }
}

extern "C" void kernel_launch(void* const* d_in, const int* in_sizes, int n_in,
                              void* d_out, int out_size, void* d_ws, size_t ws_size,
                              hipStream_t stream) {
    const float* h    = (const float*)d_in[0];
    const float* a    = (const float*)d_in[1];
    const float* kern = (const float*)d_in[2];
    // d_in[3] = att_k1: cancels in row-softmax, unused
    const float* ak2  = (const float*)d_in[4];
    const float* bias = (const float*)d_in[5];
    float* out = (float*)d_out;

    char* ws = (char*)d_ws;
    size_t o_feat  = 0;                                   // 768000 f = 3,072,000 B
    size_t o_e2    = o_feat  + 3072000;                   //  24000 f =    96,000 B
    size_t o_nmask = o_e2    + 96000;                     //   6000 f =  24,000 B (pad)
    size_t o_G     = o_nmask + 24064;                     // 108288 * 16 B = 1,732,608 B
    size_t o_part  = o_G     + 1732608;                   // 3008 * 2304 * 4 B = 27,721,728 B
    float*  feat  = (float*)(ws + o_feat);
    float*  e2    = (float*)(ws + o_e2);
    float*  nmask = (float*)(ws + o_nmask);
    bf16x8* G     = (bf16x8*)(ws + o_G);
    float*  part  = (float*)(ws + o_part);

    k_feat<<<dim3(B_ * N_), dim3(128), 0, stream>>>(h, kern, ak2, feat, e2, nmask);
    int gtot = B_ * NCH_ * KT_ * 64;
    k_G   <<<dim3((gtot + 255) / 256), dim3(256), 0, stream>>>(feat, e2, G);
    k_main<<<dim3(B_ * NROWT_ * S_), dim3(256), 0, stream>>>(a, G, part);
    k_red <<<dim3(B_ * NROWT_), dim3(256), 0, stream>>>(part, bias, nmask, out);
}